// Round 10
// baseline (239.943 us; speedup 1.0000x reference)
//
#include <hip/hip_runtime.h>

#define IMG_H 4096
#define IMG_W 4096
#define RAD 4
#define TSX 128
#define TSY 16
#define LROWS (TSY + 2*RAD)   // 24
#define LCOLS (TSX + 2*RAD)   // 136; stride 136 floats = 544B, 16B-aligned

__device__ __forceinline__ int reflect_idx(int i, int n) {
    i = (i < 0) ? -i : i;
    i = (i >= n) ? (2 * n - 2 - i) : i;
    return i;
}

__global__ __launch_bounds__(256, 4) void bilateral_kernel(const float* __restrict__ in,
                                                           float* __restrict__ out) {
    __shared__ float tile[LROWS * LCOLS];   // 3264 floats = 13056 B
    const int bx = blockIdx.x * TSX;
    const int by = blockIdx.y * TSY;
    const int tid = threadIdx.x;

    const bool interior = (blockIdx.x > 0) && (blockIdx.x < (int)gridDim.x - 1) &&
                          (blockIdx.y > 0) && (blockIdx.y < (int)gridDim.y - 1);
    if (interior) {
        // 24 rows x 34 float4 = 816 coalesced 16B chunks, linear into LDS.
        const float* src = in + (size_t)(by - RAD) * IMG_W + (bx - RAD);
#pragma unroll
        for (int it = 0; it < 4; ++it) {
            int i = tid + it * 256;
            if (i < 816) {
                int row = i / 34;
                int col = i - row * 34;
                float4 q = *reinterpret_cast<const float4*>(src + row * IMG_W + col * 4);
                *reinterpret_cast<float4*>(&tile[row * 136 + col * 4]) = q;
            }
        }
    } else {
        for (int i = tid; i < LROWS * LCOLS; i += 256) {
            int ly = i / 136;
            int lx = i - ly * 136;
            int gy = reflect_idx(by + ly - RAD, IMG_H);
            int gx = reflect_idx(bx + lx - RAD, IMG_W);
            tile[ly * 136 + lx] = in[gy * IMG_W + gx];
        }
    }
    __syncthreads();

    // 256 threads = 16 tx x 16 ty. Each thread: TWO quads of pixels,
    // at x0 = 4*tx and x0+64 (lane-stride-4 LDS reads -> 2-way aliasing only).
    const int tx = tid & 15;
    const int ty = tid >> 4;
    const int x0 = tx * 4;

    constexpr float LOG2E = 1.4426950408889634f;
    constexpr float KR   = -50.0f * LOG2E;          // -log2e/(2*sigma_r^2)
    constexpr float S15  = 32768.0f;                // 2^23 / 2^8
    constexpr float KRS  = KR * S15;                // prescaled (2^-8 folded)
    constexpr float NEG2KRS = -2.0f * KRS;
    constexpr float SCS  = (-LOG2E / 18.0f) * S15;  // spatial log-weight, prescaled
    // Schraudolph bias / 2^8  +  2^23 (float->int via mantissa trick, no v_cvt)
    constexpr float BIAS = (127.0f - 0.04303f) * S15 + 8388608.0f;

    // Per-pixel linear coefficient B = -2*KR'*c. (Dropped KR*c^2 term is a
    // per-pixel constant factor on w -> cancels in num/den.)
    float B[8], n[8], d[8];
    {
        const float* crow = &tile[(ty + RAD) * 136 + x0 + RAD];
        float4 cA = *reinterpret_cast<const float4*>(crow);        // x0+4
        float4 cB = *reinterpret_cast<const float4*>(crow + 64);   // x0+68
        B[0] = NEG2KRS * cA.x; B[1] = NEG2KRS * cA.y;
        B[2] = NEG2KRS * cA.z; B[3] = NEG2KRS * cA.w;
        B[4] = NEG2KRS * cB.x; B[5] = NEG2KRS * cB.y;
        B[6] = NEG2KRS * cB.z; B[7] = NEG2KRS * cB.w;
    }
#pragma unroll
    for (int p = 0; p < 8; ++p) { n[p] = 0.f; d[p] = 0.f; }

    const float* rowp = &tile[ty * 136 + x0];

#pragma unroll 1
    for (int r = 0; r < 9; ++r) {
        // Named float4s (no alloca -> cannot be demoted to scratch).
        const float4 qa0 = *reinterpret_cast<const float4*>(rowp);
        const float4 qa1 = *reinterpret_cast<const float4*>(rowp + 4);
        const float4 qa2 = *reinterpret_cast<const float4*>(rowp + 8);
        const float4 qb0 = *reinterpret_cast<const float4*>(rowp + 64);
        const float4 qb1 = *reinterpret_cast<const float4*>(rowp + 68);
        const float4 qb2 = *reinterpret_cast<const float4*>(rowp + 72);
        rowp += 136;

        auto VA = [&](int i) -> float {
            switch (i) {
                case 0:  return qa0.x; case 1:  return qa0.y; case 2:  return qa0.z; case 3:  return qa0.w;
                case 4:  return qa1.x; case 5:  return qa1.y; case 6:  return qa1.z; case 7:  return qa1.w;
                case 8:  return qa2.x; case 9:  return qa2.y; case 10: return qa2.z; case 11: return qa2.w;
            }
            return 0.f;
        };
        auto VB = [&](int i) -> float {
            switch (i) {
                case 0:  return qb0.x; case 1:  return qb0.y; case 2:  return qb0.z; case 3:  return qb0.w;
                case 4:  return qb1.x; case 5:  return qb1.y; case 6:  return qb1.z; case 7:  return qb1.w;
                case 8:  return qb2.x; case 9:  return qb2.y; case 10: return qb2.z; case 11: return qb2.w;
            }
            return 0.f;
        };

        // Fold spatial dy-term into the (prescaled) bias; named scalars only.
        int e = r - 4;
        float syf = (float)(e * e) * SCS;
        const float sc0 = syf + (16.0f * SCS + BIAS);
        const float sc1 = syf + (9.0f  * SCS + BIAS);
        const float sc2 = syf + (4.0f  * SCS + BIAS);
        const float sc3 = syf + (1.0f  * SCS + BIAS);
        const float sc4 = syf + (0.0f  * SCS + BIAS);
        auto SCB = [&](int i) -> float {
            switch (i) {
                case 0: return sc0; case 1: return sc1; case 2: return sc2;
                case 3: return sc3; case 4: return sc4; case 5: return sc3;
                case 6: return sc2; case 7: return sc1; case 8: return sc0;
            }
            return 0.f;
        };

#pragma unroll
        for (int dx = 0; dx < 9; ++dx) {
            const float sc = SCB(dx);
#pragma unroll
            for (int p = 0; p < 4; ++p) {
                {   // group A
                    float vv = VA(dx + p);
                    float t  = fmaf(KRS, vv, B[p]);
                    float y  = fmaf(vv, t, sc);            // 2^23 + schraudolph/2^8
                    float w  = __int_as_float(__float_as_int(y) << 8);  // no v_cvt
                    n[p] = fmaf(w, vv, n[p]);
                    d[p] += w;
                }
                {   // group B (+64 px)
                    float vv = VB(dx + p);
                    float t  = fmaf(KRS, vv, B[p + 4]);
                    float y  = fmaf(vv, t, sc);
                    float w  = __int_as_float(__float_as_int(y) << 8);
                    n[p + 4] = fmaf(w, vv, n[p + 4]);
                    d[p + 4] += w;
                }
            }
        }
    }

    float4 oA, oB;
    oA.x = n[0] * __builtin_amdgcn_rcpf(d[0]);
    oA.y = n[1] * __builtin_amdgcn_rcpf(d[1]);
    oA.z = n[2] * __builtin_amdgcn_rcpf(d[2]);
    oA.w = n[3] * __builtin_amdgcn_rcpf(d[3]);
    oB.x = n[4] * __builtin_amdgcn_rcpf(d[4]);
    oB.y = n[5] * __builtin_amdgcn_rcpf(d[5]);
    oB.z = n[6] * __builtin_amdgcn_rcpf(d[6]);
    oB.w = n[7] * __builtin_amdgcn_rcpf(d[7]);

    float* orow = &out[(size_t)(by + ty) * IMG_W + bx + x0];
    *reinterpret_cast<float4*>(orow)      = oA;
    *reinterpret_cast<float4*>(orow + 64) = oB;
}

extern "C" void kernel_launch(void* const* d_in, const int* in_sizes, int n_in,
                              void* d_out, int out_size, void* d_ws, size_t ws_size,
                              hipStream_t stream) {
    const float* in = (const float*)d_in[0];
    float* out = (float*)d_out;
    dim3 grid(IMG_W / TSX, IMG_H / TSY);
    bilateral_kernel<<<grid, 256, 0, stream>>>(in, out);
}